// Round 1
// baseline (327.994 us; speedup 1.0000x reference)
//
#include <hip/hip_runtime.h>
#include <hip/hip_bf16.h>

// LightGCN layer: out = adj @ (x * (u >= 0.1) / 0.9)
// x: [16384,64] f32, adj: [16384,16384] f32, u: [16384,64] f32, out: [16384,64] f32
//
// Strategy: bf16 MFMA (16x16x32). adj (1.07 GB) streamed once from HBM as fp32,
// converted in-register to bf16 A-fragments. B (dropout-applied x, 2 MB bf16) is
// precomputed in fragment-linear layout in d_ws and stays L2-resident.
// GEMM kernel uses no LDS and no barriers: each wave computes a 16x64 output tile.

#define NN 16384
#define DD 64

typedef __attribute__((ext_vector_type(8))) short short8;
typedef __attribute__((ext_vector_type(4))) float floatx4;

static __device__ __forceinline__ short bf16b(float f) {
    union { __hip_bfloat16 h; short s; } cv;
    cv.h = __float2bfloat16(f);
    return cv.s;
}

// Writes B in MFMA fragment-linear order:
// chunk c = s*256 + f*64 + lane  (s = K-step of 32, f = 16-col group, lane = 0..63)
// shorts at c*8: element j = B[s*32 + (lane>>4)*8 + j][f*16 + (lane&15)]
__global__ void __launch_bounds__(256) prep_kernel(const float* __restrict__ x,
                                                   const float* __restrict__ u,
                                                   short* __restrict__ bfrag) {
    int c = blockIdx.x * 256 + threadIdx.x;   // 0..131071
    int lane = c & 63;
    int f = (c >> 6) & 3;
    int s = c >> 8;                            // 0..511
    int col = f * 16 + (lane & 15);
    int k0 = s * 32 + (lane >> 4) * 8;
    short8 v;
#pragma unroll
    for (int j = 0; j < 8; ++j) {
        int idx = (k0 + j) * DD + col;
        float xv = x[idx];
        float uv = u[idx];
        float xd = (uv >= 0.1f) ? xv * (1.0f / 0.9f) : 0.0f;
        v[j] = bf16b(xd);
    }
    *reinterpret_cast<short8*>(bfrag + (size_t)c * 8) = v;
}

__global__ void __launch_bounds__(256) gemm_kernel(const float* __restrict__ adj,
                                                   const short* __restrict__ bfrag,
                                                   float* __restrict__ out) {
    const int lane = threadIdx.x & 63;
    const int wave = threadIdx.x >> 6;
    const int row0 = blockIdx.x * 64 + wave * 16;   // wave's 16 rows
    const int r  = lane & 15;                       // A row within tile
    const int kg = lane >> 4;                       // k-group 0..3

    const float* aptr = adj + (size_t)(row0 + r) * NN + kg * 8;
    const short* bp   = bfrag + (size_t)lane * 8;

    floatx4 acc0 = {0.f, 0.f, 0.f, 0.f};
    floatx4 acc1 = {0.f, 0.f, 0.f, 0.f};
    floatx4 acc2 = {0.f, 0.f, 0.f, 0.f};
    floatx4 acc3 = {0.f, 0.f, 0.f, 0.f};

#pragma unroll 4
    for (int s = 0; s < NN / 32; ++s) {
        // A fragment: 8 contiguous fp32 of this lane's row -> bf16x8
        floatx4 alo = *reinterpret_cast<const floatx4*>(aptr);
        floatx4 ahi = *reinterpret_cast<const floatx4*>(aptr + 4);
        aptr += 32;
        short8 a;
        a[0] = bf16b(alo.x); a[1] = bf16b(alo.y); a[2] = bf16b(alo.z); a[3] = bf16b(alo.w);
        a[4] = bf16b(ahi.x); a[5] = bf16b(ahi.y); a[6] = bf16b(ahi.z); a[7] = bf16b(ahi.w);

        // B fragments: 16B per lane, fragment-linear, L2-resident
        short8 b0 = *reinterpret_cast<const short8*>(bp);
        short8 b1 = *reinterpret_cast<const short8*>(bp + 512);
        short8 b2 = *reinterpret_cast<const short8*>(bp + 1024);
        short8 b3 = *reinterpret_cast<const short8*>(bp + 1536);
        bp += 2048;

        acc0 = __builtin_amdgcn_mfma_f32_16x16x32_bf16(a, b0, acc0, 0, 0, 0);
        acc1 = __builtin_amdgcn_mfma_f32_16x16x32_bf16(a, b1, acc1, 0, 0, 0);
        acc2 = __builtin_amdgcn_mfma_f32_16x16x32_bf16(a, b2, acc2, 0, 0, 0);
        acc3 = __builtin_amdgcn_mfma_f32_16x16x32_bf16(a, b3, acc3, 0, 0, 0);
    }

    // C/D layout: col = lane&15, row = (lane>>4)*4 + j   [measured m89/m91]
    const int orow = row0 + kg * 4;
    float* op = out + (size_t)orow * DD + r;
#pragma unroll
    for (int j = 0; j < 4; ++j) {
        op[(size_t)j * DD + 0]  = acc0[j];
        op[(size_t)j * DD + 16] = acc1[j];
        op[(size_t)j * DD + 32] = acc2[j];
        op[(size_t)j * DD + 48] = acc3[j];
    }
}

extern "C" void kernel_launch(void* const* d_in, const int* in_sizes, int n_in,
                              void* d_out, int out_size, void* d_ws, size_t ws_size,
                              hipStream_t stream) {
    const float* x   = (const float*)d_in[0];
    const float* adj = (const float*)d_in[1];
    const float* u   = (const float*)d_in[2];
    float* out = (float*)d_out;
    short* bfrag = (short*)d_ws;   // 16384*64 bf16 = 2 MB

    prep_kernel<<<dim3(512), dim3(256), 0, stream>>>(x, u, bfrag);
    gemm_kernel<<<dim3(256), dim3(256), 0, stream>>>(adj, bfrag, out);
}

// Round 2
// 304.966 us; speedup vs baseline: 1.0755x; 1.0755x over previous
//
#include <hip/hip_runtime.h>
#include <hip/hip_bf16.h>

// LightGCN layer: out = adj @ (x * (u >= 0.1) / 0.9)
// x: [16384,64] f32, adj: [16384,16384] f32, u: [16384,64] f32, out: [16384,64] f32
//
// Round 2: intra-block K-split for occupancy. 1024 blocks x 8 waves; each block
// owns a 16-row output tile, each wave covers K/8 = 2048 and accumulates its own
// MFMA fragments; deterministic LDS reduction + coalesced fp32 store.
// adj (1.07 GB) is read exactly once; B (2 MB bf16, fragment-linear in d_ws)
// stays L2-resident per XCD.

#define NN 16384
#define DD 64

typedef __attribute__((ext_vector_type(8))) short short8;
typedef __attribute__((ext_vector_type(4))) float floatx4;

static __device__ __forceinline__ short bf16b(float f) {
    union { __hip_bfloat16 h; short s; } cv;
    cv.h = __float2bfloat16(f);
    return cv.s;
}

// Writes B in MFMA fragment-linear order:
// chunk c = s*256 + f*64 + lane  (s = K-step of 32, f = 16-col group, lane = 0..63)
// shorts at c*8: element j = B[s*32 + (lane>>4)*8 + j][f*16 + (lane&15)]
__global__ void __launch_bounds__(256) prep_kernel(const float* __restrict__ x,
                                                   const float* __restrict__ u,
                                                   short* __restrict__ bfrag) {
    int c = blockIdx.x * 256 + threadIdx.x;   // 0..131071
    int lane = c & 63;
    int f = (c >> 6) & 3;
    int s = c >> 8;                            // 0..511
    int col = f * 16 + (lane & 15);
    int k0 = s * 32 + (lane >> 4) * 8;
    short8 v;
#pragma unroll
    for (int j = 0; j < 8; ++j) {
        int idx = (k0 + j) * DD + col;
        float xv = x[idx];
        float uv = u[idx];
        float xd = (uv >= 0.1f) ? xv * (1.0f / 0.9f) : 0.0f;
        v[j] = bf16b(xd);
    }
    *reinterpret_cast<short8*>(bfrag + (size_t)c * 8) = v;
}

#define KSPLIT 8
#define KSTEPS (NN / 32 / KSPLIT)   // 64 K-steps of 32 per wave
#define LDS_STRIDE 17               // pad 16 -> 17 to break bank conflicts

__global__ void __launch_bounds__(512, 4) gemm_kernel(const float* __restrict__ adj,
                                                      const short* __restrict__ bfrag,
                                                      float* __restrict__ out) {
    __shared__ float lds[KSPLIT * 64 * LDS_STRIDE];   // 34,816 B

    const int lane = threadIdx.x & 63;
    const int wave = threadIdx.x >> 6;                // 0..7 = K-chunk
    const int row0 = blockIdx.x * 16;                 // block's 16 rows
    const int r  = lane & 15;                         // A row within tile
    const int kg = lane >> 4;                         // k-subgroup 0..3

    const float* aptr = adj + (size_t)(row0 + r) * NN + wave * (NN / KSPLIT) + kg * 8;
    const short* bp   = bfrag + (size_t)(wave * KSTEPS) * 2048 + (size_t)lane * 8;

    floatx4 acc0 = {0.f, 0.f, 0.f, 0.f};
    floatx4 acc1 = {0.f, 0.f, 0.f, 0.f};
    floatx4 acc2 = {0.f, 0.f, 0.f, 0.f};
    floatx4 acc3 = {0.f, 0.f, 0.f, 0.f};

#pragma unroll 2
    for (int s = 0; s < KSTEPS; ++s) {
        // A fragment: 8 contiguous fp32 of this lane's row -> bf16x8
        floatx4 alo = *reinterpret_cast<const floatx4*>(aptr);
        floatx4 ahi = *reinterpret_cast<const floatx4*>(aptr + 4);
        aptr += 32;
        short8 a;
        a[0] = bf16b(alo.x); a[1] = bf16b(alo.y); a[2] = bf16b(alo.z); a[3] = bf16b(alo.w);
        a[4] = bf16b(ahi.x); a[5] = bf16b(ahi.y); a[6] = bf16b(ahi.z); a[7] = bf16b(ahi.w);

        // B fragments: 16B per lane, fragment-linear, L2-resident
        short8 b0 = *reinterpret_cast<const short8*>(bp);
        short8 b1 = *reinterpret_cast<const short8*>(bp + 512);
        short8 b2 = *reinterpret_cast<const short8*>(bp + 1024);
        short8 b3 = *reinterpret_cast<const short8*>(bp + 1536);
        bp += 2048;

        acc0 = __builtin_amdgcn_mfma_f32_16x16x32_bf16(a, b0, acc0, 0, 0, 0);
        acc1 = __builtin_amdgcn_mfma_f32_16x16x32_bf16(a, b1, acc1, 0, 0, 0);
        acc2 = __builtin_amdgcn_mfma_f32_16x16x32_bf16(a, b2, acc2, 0, 0, 0);
        acc3 = __builtin_amdgcn_mfma_f32_16x16x32_bf16(a, b3, acc3, 0, 0, 0);
    }

    // Stash partial fragments: lds[wave][lane][frag*4+j]
    float* my = lds + (wave * 64 + lane) * LDS_STRIDE;
#pragma unroll
    for (int j = 0; j < 4; ++j) {
        my[0 * 4 + j]  = acc0[j];
        my[1 * 4 + j]  = acc1[j];
        my[2 * 4 + j]  = acc2[j];
        my[3 * 4 + j]  = acc3[j];
    }
    __syncthreads();

    // Deterministic reduction over the 8 K-chunks; coalesced output write.
    // Output element e (0..1023): row = e>>6, col = e&63.
    // acc mapping: row = kg*4 + j, col = f*16 + r  =>
    //   lane_s = (row>>2)*16 + (col&15), reg = (col>>4)*4 + (row&3)
#pragma unroll
    for (int e0 = 0; e0 < 2; ++e0) {
        int e = e0 * 512 + threadIdx.x;
        int row = e >> 6;
        int col = e & 63;
        int lidx = ((row >> 2) * 16 + (col & 15)) * LDS_STRIDE + (col >> 4) * 4 + (row & 3);
        float sum = 0.f;
#pragma unroll
        for (int w = 0; w < KSPLIT; ++w)
            sum += lds[w * 64 * LDS_STRIDE + lidx];
        out[(size_t)(row0 + row) * DD + col] = sum;
    }
}

extern "C" void kernel_launch(void* const* d_in, const int* in_sizes, int n_in,
                              void* d_out, int out_size, void* d_ws, size_t ws_size,
                              hipStream_t stream) {
    const float* x   = (const float*)d_in[0];
    const float* adj = (const float*)d_in[1];
    const float* u   = (const float*)d_in[2];
    float* out = (float*)d_out;
    short* bfrag = (short*)d_ws;   // 16384*64 bf16 = 2 MB

    prep_kernel<<<dim3(512), dim3(256), 0, stream>>>(x, u, bfrag);
    gemm_kernel<<<dim3(NN / 16), dim3(512), 0, stream>>>(adj, bfrag, out);
}

// Round 3
// 245.754 us; speedup vs baseline: 1.3346x; 1.2409x over previous
//
#include <hip/hip_runtime.h>
#include <hip/hip_bf16.h>

// LightGCN layer: out = adj @ (x * (u >= 0.1) / 0.9)
// x: [16384,64] f32, adj: [16384,16384] f32, u: [16384,64] f32, out: [16384,64] f32
//
// Round 3: make every HBM access lane-contiguous (T14 async-stage split).
//  - 256 blocks x 256 thr (4 waves). Block owns 64 rows; wave w owns rows w*16..+15
//    across the FULL K => no reduction epilogue.
//  - K processed in 64 phases of 256 floats. Per phase:
//      issue B global_load_lds (bf16 frag-linear, 1KB/instr) + A global->reg loads
//      (16 x 1KB contiguous dwordx4 per wave)  [prefetch t+1]
//      compute phase t from LDS (1 A ds_read_b128 + 4 B ds_read_b128 + 4 MFMA /K-step)
//      cvt A regs -> bf16, ds_write into fragment-chunk layout; __syncthreads.
//  - LDS chunk layout byte(s,row,kg) = s*4096 + row*64 + kg*16: all LDS reads/writes
//    are contiguous per wave => bank-conflict floor, and A-frag = one ds_read_b128.

#define NN 16384
#define DD 64
#define MT 64                 // rows per block
#define KP 256                // K floats per phase
#define NPH (NN / KP)         // 64 phases
#define ABUF 32768
#define BBUF 32768

typedef __attribute__((ext_vector_type(4))) float floatx4;
typedef __attribute__((ext_vector_type(4))) short short4v;
typedef __attribute__((ext_vector_type(8))) short short8;

static __device__ __forceinline__ short bf16b(float f) {
    union { __hip_bfloat16 h; short s; } cv;
    cv.h = __float2bfloat16(f);
    return cv.s;
}

// B in MFMA fragment-linear order (unchanged, verified r1/r2):
// chunk c = s*256 + f*64 + lane; shorts at c*8:
// element j = B[s*32 + (lane>>4)*8 + j][f*16 + (lane&15)]
__global__ void __launch_bounds__(256) prep_kernel(const float* __restrict__ x,
                                                   const float* __restrict__ u,
                                                   short* __restrict__ bfrag) {
    int c = blockIdx.x * 256 + threadIdx.x;
    int lane = c & 63;
    int f = (c >> 6) & 3;
    int s = c >> 8;
    int col = f * 16 + (lane & 15);
    int k0 = s * 32 + (lane >> 4) * 8;
    short8 v;
#pragma unroll
    for (int j = 0; j < 8; ++j) {
        int idx = (k0 + j) * DD + col;
        float xv = x[idx];
        float uv = u[idx];
        float xd = (uv >= 0.1f) ? xv * (1.0f / 0.9f) : 0.0f;
        v[j] = bf16b(xd);
    }
    *reinterpret_cast<short8*>(bfrag + (size_t)c * 8) = v;
}

__global__ void __launch_bounds__(256, 1) gemm_kernel(const float* __restrict__ adj,
                                                      const short* __restrict__ bfrag,
                                                      float* __restrict__ out) {
    __shared__ char smem[2 * ABUF + 2 * BBUF];   // 128 KiB
    char* Ab0 = smem;
    char* Ab1 = smem + ABUF;
    char* Bb0 = smem + 2 * ABUF;
    char* Bb1 = smem + 2 * ABUF + BBUF;

    const int tid  = threadIdx.x;
    const int lane = tid & 63;
    const int w    = tid >> 6;            // wave 0..3
    const int r    = lane & 15;
    const int kg   = lane >> 4;
    const int row0 = blockIdx.x * MT;
    const int wrow = row0 + w * 16;       // wave's first row

    floatx4 areg[16];

    // stash-destination decomposition for lane's 4 floats (k = lane*4 .. +4)
    const int ss  = lane >> 3;            // K-step 0..7
    const int kg2 = (lane >> 1) & 3;
    const int hh  = lane & 1;

#define ISSUE_B(T, BDST)                                                          \
    {                                                                             \
        _Pragma("unroll")                                                         \
        for (int q = 0; q < 8; ++q) {                                             \
            int i = w * 8 + q;                                                    \
            const short* gp = bfrag + (size_t)(T) * 16384 + i * 512 + lane * 8;   \
            char* lp = (BDST) + i * 1024;                                         \
            __builtin_amdgcn_global_load_lds(                                     \
                (const __attribute__((address_space(1))) void*)gp,                \
                (__attribute__((address_space(3))) void*)lp, 16, 0, 0);           \
        }                                                                         \
    }

#define ISSUE_A(T)                                                                \
    {                                                                             \
        _Pragma("unroll")                                                         \
        for (int j = 0; j < 16; ++j)                                              \
            areg[j] = *reinterpret_cast<const floatx4*>(                          \
                adj + (size_t)(wrow + j) * NN + (size_t)(T) * KP + lane * 4);     \
    }

#define STASH_A(ADST)                                                             \
    {                                                                             \
        char* base_ = (ADST) + ss * 4096 + kg2 * 16 + hh * 8;                     \
        _Pragma("unroll")                                                         \
        for (int j = 0; j < 16; ++j) {                                            \
            short4v bw;                                                           \
            bw.x = bf16b(areg[j].x); bw.y = bf16b(areg[j].y);                     \
            bw.z = bf16b(areg[j].z); bw.w = bf16b(areg[j].w);                     \
            *reinterpret_cast<short4v*>(base_ + (w * 16 + j) * 64) = bw;          \
        }                                                                         \
    }

    floatx4 acc0 = {0.f, 0.f, 0.f, 0.f};
    floatx4 acc1 = {0.f, 0.f, 0.f, 0.f};
    floatx4 acc2 = {0.f, 0.f, 0.f, 0.f};
    floatx4 acc3 = {0.f, 0.f, 0.f, 0.f};

    // prologue: stage phase 0
    ISSUE_B(0, Bb0);
    ISSUE_A(0);
    STASH_A(Ab0);
    __syncthreads();

    for (int t = 0; t < NPH; ++t) {
        char* Ac = (t & 1) ? Ab1 : Ab0;
        char* Bc = (t & 1) ? Bb1 : Bb0;
        char* An = (t & 1) ? Ab0 : Ab1;
        char* Bn = (t & 1) ? Bb0 : Bb1;

        if (t + 1 < NPH) {
            ISSUE_B(t + 1, Bn);
            ISSUE_A(t + 1);
            asm volatile("" ::: "memory");   // pin prefetch issue before compute
        }

        const char* ap = Ac + (w * 16 + r) * 64 + kg * 16;
        const char* bp = Bc + lane * 16;
#pragma unroll
        for (int s = 0; s < 8; ++s) {
            short8 af = *reinterpret_cast<const short8*>(ap + s * 4096);
            short8 b0 = *reinterpret_cast<const short8*>(bp + s * 4096);
            short8 b1 = *reinterpret_cast<const short8*>(bp + s * 4096 + 1024);
            short8 b2 = *reinterpret_cast<const short8*>(bp + s * 4096 + 2048);
            short8 b3 = *reinterpret_cast<const short8*>(bp + s * 4096 + 3072);
            acc0 = __builtin_amdgcn_mfma_f32_16x16x32_bf16(af, b0, acc0, 0, 0, 0);
            acc1 = __builtin_amdgcn_mfma_f32_16x16x32_bf16(af, b1, acc1, 0, 0, 0);
            acc2 = __builtin_amdgcn_mfma_f32_16x16x32_bf16(af, b2, acc2, 0, 0, 0);
            acc3 = __builtin_amdgcn_mfma_f32_16x16x32_bf16(af, b3, acc3, 0, 0, 0);
        }

        if (t + 1 < NPH) {
            STASH_A(An);        // data-dep waits A loads; B glds (older) drain too
            __syncthreads();    // vmcnt already 0 here -> barrier is cheap
        }
    }

    // C/D: col = lane&15, row = (lane>>4)*4 + j  (verified r1/r2)
    const int orow = wrow + kg * 4;
    float* op = out + (size_t)orow * DD + r;
#pragma unroll
    for (int j = 0; j < 4; ++j) {
        op[(size_t)j * DD + 0]  = acc0[j];
        op[(size_t)j * DD + 16] = acc1[j];
        op[(size_t)j * DD + 32] = acc2[j];
        op[(size_t)j * DD + 48] = acc3[j];
    }
}

extern "C" void kernel_launch(void* const* d_in, const int* in_sizes, int n_in,
                              void* d_out, int out_size, void* d_ws, size_t ws_size,
                              hipStream_t stream) {
    const float* x   = (const float*)d_in[0];
    const float* adj = (const float*)d_in[1];
    const float* u   = (const float*)d_in[2];
    float* out = (float*)d_out;
    short* bfrag = (short*)d_ws;   // 16384*64 bf16 = 2 MB

    prep_kernel<<<dim3(512), dim3(256), 0, stream>>>(x, u, bfrag);
    gemm_kernel<<<dim3(NN / MT), dim3(256), 0, stream>>>(adj, bfrag, out);
}